// Round 7
// baseline (22.022 us; speedup 1.0000x reference)
//
#include <hip/hip_runtime.h>

// ROI max-pooling, TF-style integer binning (matches the JAX reference).
// Round 7: one wave per (image, roi, row-bin) -> 1792 waves. Each wave loads
// the ROI once, walks its row-bin's rows across the full ROI width with all
// 7 column-bin accumulators in registers (unrolled, static indices), giving
// 16-31 independent loads in flight per row and amortizing per-wave setup
// over ~70 px (vs ~11 in R5). wstep specialized to {2,3,4} for straight-line
// inner loops. XCD pinning + nontemporal stores kept.

#define OUT_H 7
#define OUT_W 7
#define NBIN (OUT_H * OUT_W)   // 49
#define NB 4
#define NR 64
#define NH 56
#define NW 56
#define NC 256
#define C4 (NC / 4)            // 64 float4 groups per pixel

// blocks: one wave per (b, r, oi): 4*64*7 = 1792; per image 448; per XCD 224
#define BLKS_PER_XCD_SLOT 224

typedef float v4f __attribute__((ext_vector_type(4)));

__device__ __forceinline__ v4f vmax4(v4f a, v4f b) {
    v4f r;
    r.x = fmaxf(a.x, b.x);
    r.y = fmaxf(a.y, b.y);
    r.z = fmaxf(a.z, b.z);
    r.w = fmaxf(a.w, b.w);
    return r;
}

// Pool rows [rlo, rhi) over all 7 column bins. WS > 0: compile-time wstep
// (straight-line inner loops). WS == 0: generic, runtime wstep (also covers
// the degenerate wstep==0 case, where bins 0..5 are empty and bin 6 = [w0,w1)).
template <int WS>
__device__ __forceinline__ void pool_rows(
    const v4f* __restrict__ base, int rlo, int rhi,
    int w0, int w1, int wstep_rt, v4f* acc)
{
    const int ws = (WS > 0) ? WS : wstep_rt;
    for (int h = rlo; h < rhi; ++h) {
        const v4f* rowp = base + (size_t)(h * NW) * C4;
#pragma unroll
        for (int j = 0; j < OUT_W - 1; ++j) {
            const int wb = w0 + j * ws;
            if (WS > 0) {
#pragma unroll
                for (int k = 0; k < WS; ++k)
                    acc[j] = vmax4(acc[j], rowp[(size_t)(wb + k) * C4]);
            } else {
                for (int w = wb; w < wb + ws; ++w)
                    acc[j] = vmax4(acc[j], rowp[(size_t)w * C4]);
            }
        }
        for (int w = w0 + 6 * ws; w < w1; ++w)
            acc[6] = vmax4(acc[6], rowp[(size_t)w * C4]);
    }
}

__global__ __launch_bounds__(64) void roi_pool_kernel(
    const float* __restrict__ fmap,   // [B,H,W,C]
    const float* __restrict__ rois,   // [B,R,4]
    float* __restrict__ out)          // [B,R,7,7,C]
{
    const int blk  = blockIdx.x;
    const int xcd  = blk & 7;          // image b -> XCDs {2b, 2b+1}
    const int b    = xcd >> 1;
    const int lane = threadIdx.x;      // 0..63 -> float4 channel group

    const int work = ((xcd & 1) * BLKS_PER_XCD_SLOT) + (blk >> 3); // [0,448)
    const int r    = work / OUT_H;
    const int oi   = work - r * OUT_H; // row bin

    const float* roi = rois + (size_t)(b * NR + r) * 4;
    const float r0 = roi[0], r1 = roi[1], r2 = roi[2], r3 = roi[3];
    const int h0 = (int)((float)NH * r0);
    const int w0 = (int)((float)NW * r1);
    const int h1 = (int)((float)NH * r2);
    const int w1 = (int)((float)NW * r3);

    const int hstep = (int)((float)(h1 - h0) / (float)OUT_H);
    const int wstep = (int)((float)(w1 - w0) / (float)OUT_W);

    int rlo, rhi;
    if (hstep >= 1) {
        rlo = h0 + oi * hstep;
        rhi = (oi < OUT_H - 1) ? (rlo + hstep) : h1;
    } else {
        rlo = (oi == OUT_H - 1) ? h0 : 0;
        rhi = (oi == OUT_H - 1) ? h1 : 0;
    }

    const v4f* base =
        (const v4f*)(fmap + (size_t)b * NH * NW * NC) + lane;
    // pixel (h,w): base[(h*NW + w)*C4]

    const v4f ninf = (v4f){-INFINITY, -INFINITY, -INFINITY, -INFINITY};
    v4f acc[OUT_W];
#pragma unroll
    for (int j = 0; j < OUT_W; ++j) acc[j] = ninf;

    switch (wstep) {
        case 2: pool_rows<2>(base, rlo, rhi, w0, w1, wstep, acc); break;
        case 3: pool_rows<3>(base, rlo, rhi, w0, w1, wstep, acc); break;
        case 4: pool_rows<4>(base, rlo, rhi, w0, w1, wstep, acc); break;
        default: pool_rows<0>(base, rlo, rhi, w0, w1, wstep, acc); break;
    }

    // output: bins (oi, 0..6), logical ids (b, r)
    const size_t obase = ((size_t)((b * NR + r) * NBIN + oi * OUT_W)) * NC;
#pragma unroll
    for (int j = 0; j < OUT_W; ++j) {
        v4f* o = (v4f*)(out + obase + (size_t)j * NC);
        __builtin_nontemporal_store(acc[j], o + lane);
    }
}

extern "C" void kernel_launch(void* const* d_in, const int* in_sizes, int n_in,
                              void* d_out, int out_size, void* d_ws, size_t ws_size,
                              hipStream_t stream) {
    const float* fmap = (const float*)d_in[0];
    const float* rois = (const float*)d_in[1];
    float* out = (float*)d_out;

    const int nblocks = NB * NR * OUT_H;   // 1792
    roi_pool_kernel<<<nblocks, 64, 0, stream>>>(fmap, rois, out);
}

// Round 8
// 19.311 us; speedup vs baseline: 1.1404x; 1.1404x over previous
//
#include <hip/hip_runtime.h>

// ROI max-pooling, TF-style integer binning (matches the JAX reference).
// Round 8: R5 decomposition (4 bins per 256-thread block, 12544 waves,
// 49 waves/CU) + fully static-unrolled HSxWS bin cores. Input distribution
// guarantees hstep,wstep in {2,3,4} (extent 16..31 px), so a switch over 9
// (HS,WS) cases turns each interior window into straight-line code with all
// loads independent (8-deep accumulator tree). Runtime tails (last row/col
// bins, up to ~10 px/side) use 2-wide unrolled runtime loops. XCD pinning
// (image b -> XCD pair {2b,2b+1}) + nontemporal stores kept.

#define OUT_H 7
#define OUT_W 7
#define NBIN (OUT_H * OUT_W)   // 49
#define NB 4
#define NR 64
#define NH 56
#define NW 56
#define NC 256
#define C4 (NC / 4)            // 64 float4 groups per pixel

// total bins = 12544; 4 bins/block -> 3136 blocks; per image 784; per XCD 392
#define BLKS_PER_XCD_SLOT 392

typedef float v4f __attribute__((ext_vector_type(4)));

__device__ __forceinline__ v4f vmax4(v4f a, v4f b) {
    v4f r;
    r.x = fmaxf(a.x, b.x);
    r.y = fmaxf(a.y, b.y);
    r.z = fmaxf(a.z, b.z);
    r.w = fmaxf(a.w, b.w);
    return r;
}

// Static HSxWS core: all HS*WS loads independent, 8-deep accumulator tree.
template <int HS, int WS>
__device__ __forceinline__ void pool_core(
    const v4f* __restrict__ base, int rlo, int clo, v4f* acc)
{
#pragma unroll
    for (int i = 0; i < HS; ++i) {
        const v4f* rowp = base + (size_t)((rlo + i) * NW) * C4;
#pragma unroll
        for (int j = 0; j < WS; ++j) {
            acc[(i * WS + j) & 7] =
                vmax4(acc[(i * WS + j) & 7], rowp[(size_t)(clo + j) * C4]);
        }
    }
}

// Runtime-width row segment [wlo,whi) max into acc[0..1] (2-wide unroll).
__device__ __forceinline__ void pool_row_rt(
    const v4f* __restrict__ rowp, int wlo, int whi, v4f* acc)
{
    int w = wlo;
    for (; w + 1 < whi; w += 2) {
        acc[0] = vmax4(acc[0], rowp[(size_t)w * C4]);
        acc[1] = vmax4(acc[1], rowp[(size_t)(w + 1) * C4]);
    }
    if (w < whi) acc[0] = vmax4(acc[0], rowp[(size_t)w * C4]);
}

// Full bin: static core + runtime col tail (core rows) + runtime row tail.
template <int HS, int WS>
__device__ __forceinline__ void pool_bin(
    const v4f* __restrict__ base, int rlo, int rhi, int clo, int chi, v4f* acc)
{
    pool_core<HS, WS>(base, rlo, clo, acc);
    if (chi > clo + WS) {   // col tail (last column bin)
#pragma unroll
        for (int i = 0; i < HS; ++i) {
            const v4f* rowp = base + (size_t)((rlo + i) * NW) * C4;
            pool_row_rt(rowp, clo + WS, chi, acc + 2);
        }
    }
    for (int h = rlo + HS; h < rhi; ++h) {   // row tail (last row bin)
        const v4f* rowp = base + (size_t)(h * NW) * C4;
        pool_row_rt(rowp, clo, chi, acc + 4);
    }
}

// Generic fallback (unexpected steps, incl. degenerate): runtime loops.
__device__ __forceinline__ void pool_bin_generic(
    const v4f* __restrict__ base, int rlo, int rhi, int clo, int chi, v4f* acc)
{
    for (int h = rlo; h < rhi; ++h) {
        const v4f* rowp = base + (size_t)(h * NW) * C4;
        pool_row_rt(rowp, clo, chi, acc);
    }
}

__global__ __launch_bounds__(256) void roi_pool_kernel(
    const float* __restrict__ fmap,   // [B,H,W,C]
    const float* __restrict__ rois,   // [B,R,4]
    float* __restrict__ out)          // [B,R,7,7,C]
{
    const int blk  = blockIdx.x;
    const int xcd  = blk & 7;          // image b -> XCDs {2b, 2b+1}
    const int b    = xcd >> 1;
    const int wid  = threadIdx.x >> 6; // wave id 0..3 -> bin within group
    const int lane = threadIdx.x & 63; // float4 channel group

    const int work = ((xcd & 1) * BLKS_PER_XCD_SLOT) + (blk >> 3); // [0,784)
    const int gbin = work * 4 + wid;   // [0, 3136) bin id within image
    const int r    = gbin / NBIN;
    const int bin  = gbin - r * NBIN;
    const int oi   = bin / OUT_W;
    const int oj   = bin - oi * OUT_W;

    const float* roi = rois + (size_t)(b * NR + r) * 4;
    const float r0 = roi[0], r1 = roi[1], r2 = roi[2], r3 = roi[3];
    const int h0 = (int)((float)NH * r0);
    const int w0 = (int)((float)NW * r1);
    const int h1 = (int)((float)NH * r2);
    const int w1 = (int)((float)NW * r3);

    const int hstep = (int)((float)(h1 - h0) / (float)OUT_H);
    const int wstep = (int)((float)(w1 - w0) / (float)OUT_W);

    int rlo, rhi, clo, chi;
    if (hstep >= 1) {
        rlo = h0 + oi * hstep;
        rhi = (oi < OUT_H - 1) ? (rlo + hstep) : h1;
    } else {
        rlo = (oi == OUT_H - 1) ? h0 : 0;
        rhi = (oi == OUT_H - 1) ? h1 : 0;
    }
    if (wstep >= 1) {
        clo = w0 + oj * wstep;
        chi = (oj < OUT_W - 1) ? (clo + wstep) : w1;
    } else {
        clo = (oj == OUT_W - 1) ? w0 : 0;
        chi = (oj == OUT_W - 1) ? w1 : 0;
    }

    const v4f* base =
        (const v4f*)(fmap + (size_t)b * NH * NW * NC) + lane;
    // pixel (h,w): base[(h*NW + w)*C4]

    const v4f ninf = (v4f){-INFINITY, -INFINITY, -INFINITY, -INFINITY};
    v4f acc[8];
#pragma unroll
    for (int k = 0; k < 8; ++k) acc[k] = ninf;

    const bool ok = (rhi > rlo) && (chi > clo);
    if (ok) {
        switch (hstep * 10 + wstep) {
            case 22: pool_bin<2, 2>(base, rlo, rhi, clo, chi, acc); break;
            case 23: pool_bin<2, 3>(base, rlo, rhi, clo, chi, acc); break;
            case 24: pool_bin<2, 4>(base, rlo, rhi, clo, chi, acc); break;
            case 32: pool_bin<3, 2>(base, rlo, rhi, clo, chi, acc); break;
            case 33: pool_bin<3, 3>(base, rlo, rhi, clo, chi, acc); break;
            case 34: pool_bin<3, 4>(base, rlo, rhi, clo, chi, acc); break;
            case 42: pool_bin<4, 2>(base, rlo, rhi, clo, chi, acc); break;
            case 43: pool_bin<4, 3>(base, rlo, rhi, clo, chi, acc); break;
            case 44: pool_bin<4, 4>(base, rlo, rhi, clo, chi, acc); break;
            default: pool_bin_generic(base, rlo, rhi, clo, chi, acc); break;
        }
    }

    v4f m01 = vmax4(acc[0], acc[1]);
    v4f m23 = vmax4(acc[2], acc[3]);
    v4f m45 = vmax4(acc[4], acc[5]);
    v4f m67 = vmax4(acc[6], acc[7]);
    v4f m   = vmax4(vmax4(m01, m23), vmax4(m45, m67));

    // output index uses the LOGICAL ids (b, r, bin), not blockIdx
    const size_t obase = ((size_t)((b * NR + r) * NBIN + bin)) * NC;
    v4f* o = (v4f*)(out + obase);
    __builtin_nontemporal_store(m, o + lane);
}

extern "C" void kernel_launch(void* const* d_in, const int* in_sizes, int n_in,
                              void* d_out, int out_size, void* d_ws, size_t ws_size,
                              hipStream_t stream) {
    const float* fmap = (const float*)d_in[0];
    const float* rois = (const float*)d_in[1];
    float* out = (float*)d_out;

    const int nblocks = NB * NR * NBIN / 4;   // 3136
    roi_pool_kernel<<<nblocks, 256, 0, stream>>>(fmap, rois, out);
}

// Round 10
// 16.266 us; speedup vs baseline: 1.3539x; 1.1872x over previous
//
#include <hip/hip_runtime.h>

// ROI max-pooling, TF-style integer binning (matches the JAX reference).
// Round 9 (resubmit): persistent-style balanced schedule. 1568 blocks x 256
// thr (6.1 blocks/CU -> all resident, no dispatch-round tail). Each wave
// processes 2 bins chosen via a multiplicative permutation
// (bin = j*597 mod 3136, 597 coprime to 3136=2^6*7^2) so heavy last-row/col
// bins mix with light interior bins across waves (R5's consecutive-bin
// grouping bundled the ~100px corner with last-row bins in one block).
// Inner loop = R5's compact 2x2 / 4-accumulator loop (low VGPR).
// __launch_bounds__(256,8) pins full 8-waves/SIMD occupancy.
// XCD pinning (image b -> XCD pair {2b,2b+1}) + nontemporal stores kept.

#define OUT_H 7
#define OUT_W 7
#define NBIN (OUT_H * OUT_W)   // 49
#define NB 4
#define NR 64
#define NH 56
#define NW 56
#define NC 256
#define C4 (NC / 4)            // 64 float4 groups per pixel

#define NBLOCKS 1568           // total blocks; 196 per XCD
#define BLKS_PER_XCD_SLOT 196  // image-local: (xcd&1)*196 + blk>>3 in [0,392)
#define BINS_PER_IMG (NR * NBIN)   // 3136
#define PERM_MUL 597           // coprime to 3136

typedef float v4f __attribute__((ext_vector_type(4)));

__device__ __forceinline__ v4f vmax4(v4f a, v4f b) {
    v4f r;
    r.x = fmaxf(a.x, b.x);
    r.y = fmaxf(a.y, b.y);
    r.z = fmaxf(a.z, b.z);
    r.w = fmaxf(a.w, b.w);
    return r;
}

// R5's compact window loop: 2 rows x 2 cols unrolled, 4 independent accs.
__device__ __forceinline__ v4f pool_window(
    const v4f* __restrict__ base, int rlo, int rhi, int clo, int chi)
{
    const v4f ninf = (v4f){-INFINITY, -INFINITY, -INFINITY, -INFINITY};
    v4f acc0 = ninf, acc1 = ninf, acc2 = ninf, acc3 = ninf;

    int h = rlo;
    for (; h + 1 < rhi; h += 2) {
        const v4f* r0p = base + (size_t)(h * NW) * C4;
        const v4f* r1p = r0p + (size_t)NW * C4;
        int w = clo;
        for (; w + 1 < chi; w += 2) {
            acc0 = vmax4(acc0, r0p[(size_t)w * C4]);
            acc1 = vmax4(acc1, r0p[(size_t)(w + 1) * C4]);
            acc2 = vmax4(acc2, r1p[(size_t)w * C4]);
            acc3 = vmax4(acc3, r1p[(size_t)(w + 1) * C4]);
        }
        if (w < chi) {
            acc0 = vmax4(acc0, r0p[(size_t)w * C4]);
            acc2 = vmax4(acc2, r1p[(size_t)w * C4]);
        }
    }
    if (h < rhi) {
        const v4f* r0p = base + (size_t)(h * NW) * C4;
        int w = clo;
        for (; w + 1 < chi; w += 2) {
            acc0 = vmax4(acc0, r0p[(size_t)w * C4]);
            acc1 = vmax4(acc1, r0p[(size_t)(w + 1) * C4]);
        }
        if (w < chi) acc0 = vmax4(acc0, r0p[(size_t)w * C4]);
    }
    return vmax4(vmax4(acc0, acc1), vmax4(acc2, acc3));
}

__global__ __launch_bounds__(256, 8) void roi_pool_kernel(
    const float* __restrict__ fmap,   // [B,H,W,C]
    const float* __restrict__ rois,   // [B,R,4]
    float* __restrict__ out)          // [B,R,7,7,C]
{
    const int blk  = blockIdx.x;
    const int xcd  = blk & 7;          // image b -> XCDs {2b, 2b+1}
    const int b    = xcd >> 1;
    const int wid  = threadIdx.x >> 6; // wave id 0..3
    const int lane = threadIdx.x & 63; // float4 channel group

    // image-local wave id in [0, 1568): handles bins perm(2*iw), perm(2*iw+1)
    const int ibl = ((xcd & 1) * BLKS_PER_XCD_SLOT) + (blk >> 3); // [0,392)
    const int iw  = ibl * 4 + wid;                               // [0,1568)

    const v4f* base =
        (const v4f*)(fmap + (size_t)b * NH * NW * NC) + lane;
    const float* roib = rois + (size_t)b * NR * 4;

#pragma unroll
    for (int t = 0; t < 2; ++t) {
        const int j    = 2 * iw + t;                       // [0, 3136)
        const int gbin = (j * PERM_MUL) % BINS_PER_IMG;    // permuted bin id
        const int r    = gbin / NBIN;
        const int bin  = gbin - r * NBIN;
        const int oi   = bin / OUT_W;
        const int oj   = bin - oi * OUT_W;

        const float* roi = roib + (size_t)r * 4;
        const float r0 = roi[0], r1 = roi[1], r2 = roi[2], r3 = roi[3];
        const int h0 = (int)((float)NH * r0);
        const int w0 = (int)((float)NW * r1);
        const int h1 = (int)((float)NH * r2);
        const int w1 = (int)((float)NW * r3);

        const int hstep = (int)((float)(h1 - h0) / (float)OUT_H);
        const int wstep = (int)((float)(w1 - w0) / (float)OUT_W);

        int rlo, rhi, clo, chi;
        if (hstep >= 1) {
            rlo = h0 + oi * hstep;
            rhi = (oi < OUT_H - 1) ? (rlo + hstep) : h1;
        } else {
            rlo = (oi == OUT_H - 1) ? h0 : 0;
            rhi = (oi == OUT_H - 1) ? h1 : 0;
        }
        if (wstep >= 1) {
            clo = w0 + oj * wstep;
            chi = (oj < OUT_W - 1) ? (clo + wstep) : w1;
        } else {
            clo = (oj == OUT_W - 1) ? w0 : 0;
            chi = (oj == OUT_W - 1) ? w1 : 0;
        }

        const v4f m = pool_window(base, rlo, rhi, clo, chi);

        // output index uses LOGICAL ids (b, r, bin)
        const size_t obase = ((size_t)((b * NR + r) * NBIN + bin)) * NC;
        v4f* o = (v4f*)(out + obase);
        __builtin_nontemporal_store(m, o + lane);
    }
}

extern "C" void kernel_launch(void* const* d_in, const int* in_sizes, int n_in,
                              void* d_out, int out_size, void* d_ws, size_t ws_size,
                              hipStream_t stream) {
    const float* fmap = (const float*)d_in[0];
    const float* rois = (const float*)d_in[1];
    float* out = (float*)d_out;

    roi_pool_kernel<<<NBLOCKS, 256, 0, stream>>>(fmap, rois, out);
}